// Round 6
// baseline (1096.464 us; speedup 1.0000x reference)
//
#include <hip/hip_runtime.h>
#include <cstdint>
#include <cstddef>

#define NN 50000
#define EE 1000000
#define RPSTRIDE 50016   // rowptr stride per branch (ints)
#define NBK 196          // dst buckets (dst>>8), 196*256 = 50176 >= NN

typedef __attribute__((ext_vector_type(8))) short bf16x8;
typedef __attribute__((ext_vector_type(4))) float f32x4;

__device__ __forceinline__ unsigned short f2bf(float f) {
    union { unsigned int i; float f; } v; v.f = f;
    unsigned int u = v.i;
    u = u + 0x7FFFu + ((u >> 16) & 1u);
    return (unsigned short)(u >> 16);
}

// truncation split: v == bf16(hi) + ~bf16(lo), residual ~2^-16 rel
__device__ __forceinline__ void split2(float v, short& hi, short& lo) {
    union { float f; unsigned int u; } a; a.f = v;
    unsigned short h16 = (unsigned short)(a.u >> 16);
    union { unsigned int u; float f; } hf; hf.u = ((unsigned int)h16) << 16;
    union { float f; unsigned int u; } b; b.f = v - hf.f;
    hi = (short)h16;
    lo = (short)(b.u >> 16);
}

// ---------- workspace layout (byte offsets) ----------
#define OFF_WHL    ((size_t)0)         // 2*1024*64 bf16 (hi|lo, frag-packed) = 262144
#define OFF_WSPP   ((size_t)262144)    // 64*4 f32
#define OFF_BIAS01 ((size_t)263168)    // 64 f32
#define OFF_W1PQT  ((size_t)263424)    // 3*64*128 f32
#define OFF_BIASPQ ((size_t)361728)    // 3*128 f32
#define OFF_WSAGET ((size_t)363264)    // 128*64 f32
#define OFF_BIAS21 ((size_t)396032)    // 64 f32
#define OFF_BNF    ((size_t)396288)    // 3*192 f32 (+pad to 2560)
#define OFF_W2BF   ((size_t)398848)    // 3*64*64 bf16 = 24576
#define OFF_INVCNT ((size_t)423424)    // N f32
#define OFF_PBUF   ((size_t)623424)    // N f32
#define OFF_ZBUF   ((size_t)823424)    // N f32
#define OFF_RP3    ((size_t)1023424)   // 3*RPSTRIDE i32 = 600192
#define OFF_PARTS  ((size_t)1623616)   // 3*256 i32 (+pad 4096)
#define OFF_DEG3   ((size_t)1627712)   // 3*N i32 = 600000
#define OFF_GHEAD  ((size_t)2227712)   // 3*NBK i32 (+pad 600000)
#define OFF_O      ((size_t)2827712)   // N f32   = 200000
#define OFF_SORT3  ((size_t)3027712)   // 3*E i32 = 12000000
#define OFF_H      ((size_t)15027712)  // N*64 f32 = 12800000
#define OFF_PQ     ((size_t)27827712)  // N*128 f32 = 25600000
#define OFF_Y1     ((size_t)53427712)  // N*64 f32
#define OFF_AGG    ((size_t)66227712)  // N*64 f32 (end 79027712)
#define OFF_Y2     OFF_PQ              // overlay: PQ dead after edgeconv
#define OFF_EBUCK3 OFF_Y1              // overlay: 3*E u32, dead before edgeconv

// ---------- K1: weight prep / folding ----------
__global__ __launch_bounds__(256) void k_prep(
    const float* __restrict__ Wspf, const float* __restrict__ bspf,
    const float* __restrict__ W011, const float* __restrict__ b011,
    const float* __restrict__ W012, const float* __restrict__ b012,
    const float* __restrict__ bn01,
    const float* __restrict__ e1W1, const float* __restrict__ e1b1,
    const float* __restrict__ e1b2, const float* __restrict__ bn11,
    const float* __restrict__ e2W1, const float* __restrict__ e2b1,
    const float* __restrict__ e2b2, const float* __restrict__ bn12,
    const float* __restrict__ e3W1, const float* __restrict__ e3b1,
    const float* __restrict__ e3b2, const float* __restrict__ bn13,
    const float* __restrict__ e1W2, const float* __restrict__ e2W2,
    const float* __restrict__ e3W2,
    const float* __restrict__ s21Wl, const float* __restrict__ s21bl,
    const float* __restrict__ s21Wr, const float* __restrict__ bn21,
    unsigned short* __restrict__ Whl, float* __restrict__ WspP, float* __restrict__ bias01,
    float* __restrict__ W1pqT, float* __restrict__ biasPQ,
    float* __restrict__ WsageT, float* __restrict__ bias21, float* __restrict__ bnf,
    unsigned short* __restrict__ W2bf)
{
    int idx = blockIdx.x * 256 + threadIdx.x;
    if (idx < 131072) {
        int hl = idx >> 16;
        int r = idx & 65535;
        int kchunk = r >> 11;
        int r2 = r & 2047;
        int blk = r2 >> 9;
        int r3 = r2 & 511;
        int lane = r3 >> 3;
        int j = r3 & 7;
        int n = lane & 15, quad = lane >> 4;
        int k = kchunk * 32 + quad * 8 + j;
        int c = blk * 16 + n;
        float s = bn01[c] * rsqrtf(bn01[192 + c] + 1e-5f);
        float w = ((k < 512) ? W012[c * 512 + k] : W011[c * 576 + (k - 512)]) * s;
        short hi, lo;
        split2(w, hi, lo);
        Whl[idx] = (unsigned short)(hl ? lo : hi);
    } else if (idx < 131072 + 24576) {
        int r = idx - 131072;
        int b = r >> 13; r &= 8191;
        int k = r >> 7, cp = r & 127;
        const float* W1 = (b == 0) ? e1W1 : (b == 1) ? e2W1 : e3W1;
        float val;
        if (cp < 64) val = W1[cp * 128 + k] - W1[cp * 128 + 64 + k];
        else         val = W1[(cp - 64) * 128 + 64 + k];
        W1pqT[b * 8192 + k * 128 + cp] = val;
    } else if (idx < 131072 + 24576 + 8192) {
        int r = idx - (131072 + 24576);
        int k = r >> 6, c = r & 63;
        float s = bn21[c] * rsqrtf(bn21[192 + c] + 1e-5f);
        float w = (k < 64) ? s21Wl[c * 64 + k] : s21Wr[c * 64 + (k - 64)];
        WsageT[k * 64 + c] = w * s;
    } else if (idx < 131072 + 24576 + 8192 + 64) {
        int c = idx - (131072 + 24576 + 8192);
        float s01 = bn01[c] * rsqrtf(bn01[192 + c] + 1e-5f);
        float wsp0 = 0.f, wsp1 = 0.f, wsp2 = 0.f, wsp3 = 0.f, bacc = 0.f;
        for (int j = 0; j < 64; j++) {
            float w = W011[c * 576 + 512 + j];
            wsp0 += w * Wspf[j * 4 + 0];
            wsp1 += w * Wspf[j * 4 + 1];
            wsp2 += w * Wspf[j * 4 + 2];
            wsp3 += w * Wspf[j * 4 + 3];
            bacc += w * bspf[j];
        }
        WspP[c * 4 + 0] = wsp0 * s01; WspP[c * 4 + 1] = wsp1 * s01;
        WspP[c * 4 + 2] = wsp2 * s01; WspP[c * 4 + 3] = wsp3 * s01;
        bias01[c] = (b011[c] + b012[c] + bacc) * s01 + (bn01[64 + c] - bn01[128 + c] * s01);
        float s21 = bn21[c] * rsqrtf(bn21[192 + c] + 1e-5f);
        bias21[c] = s21bl[c] * s21 + (bn21[64 + c] - bn21[128 + c] * s21);
        const float* b1a[3] = { e1b1, e2b1, e3b1 };
        const float* b2a[3] = { e1b2, e2b2, e3b2 };
        const float* bna[3] = { bn11, bn12, bn13 };
#pragma unroll
        for (int b = 0; b < 3; b++) {
            float s = bna[b][c] * rsqrtf(bna[b][192 + c] + 1e-5f);
            float tr = bna[b][64 + c] - bna[b][128 + c] * s;
            bnf[b * 192 + c] = s;
            bnf[b * 192 + 64 + c] = b2a[b][c] * s + tr;
            bnf[b * 192 + 128 + c] = tr;
            biasPQ[b * 128 + c] = b1a[b][c];
            biasPQ[b * 128 + 64 + c] = 0.f;
        }
    } else if (idx < 131072 + 24576 + 8192 + 64 + 12288) {
        int r = idx - (131072 + 24576 + 8192 + 64);
        int b = r >> 12, i = r & 4095;
        const float* W2 = (b == 0) ? e1W2 : (b == 1) ? e2W2 : e3W2;
        W2bf[b * 4096 + i] = f2bf(W2[i]);
    }
}

// ---------- per-branch degree histogram ----------
__global__ __launch_bounds__(256) void k_hist3(
    const int* __restrict__ dst, const int* __restrict__ attr, int* __restrict__ deg3)
{
    int e = blockIdx.x * 256 + threadIdx.x;
    if (e < EE) {
        int d = dst[e], a = attr[e];
        atomicAdd(&deg3[2 * NN + d], 1);
        if (a >= 0) atomicAdd(&deg3[0 * NN + d], 1);
        if (a <= 0) atomicAdd(&deg3[1 * NN + d], 1);
    }
}

__global__ __launch_bounds__(256) void k_psum(const int* __restrict__ deg3, int* __restrict__ parts)
{
    int b = blockIdx.y;
    int i = blockIdx.x * 256 + threadIdx.x;
    int v = (i < NN) ? deg3[b * NN + i] : 0;
#pragma unroll
    for (int off = 32; off > 0; off >>= 1) v += __shfl_xor(v, off);
    __shared__ int ws4[4];
    int wid = threadIdx.x >> 6;
    if ((threadIdx.x & 63) == 0) ws4[wid] = v;
    __syncthreads();
    if (threadIdx.x == 0)
        parts[b * 256 + blockIdx.x] = ws4[0] + ws4[1] + ws4[2] + ws4[3];
}

__global__ __launch_bounds__(256) void k_pscan(int* __restrict__ parts)
{
    __shared__ int sbuf[256];
    int tid = threadIdx.x;
    for (int b = 0; b < 3; b++) {
        int v = (tid < 196) ? parts[b * 256 + tid] : 0;
        sbuf[tid] = v;
        __syncthreads();
        for (int off = 1; off < 256; off <<= 1) {
            int t = (tid >= off) ? sbuf[tid - off] : 0;
            __syncthreads();
            sbuf[tid] += t;
            __syncthreads();
        }
        if (tid < 196) parts[b * 256 + tid] = sbuf[tid] - v;  // exclusive
        __syncthreads();
    }
}

__global__ __launch_bounds__(256) void k_scanfix(
    const int* __restrict__ deg3, const int* __restrict__ parts, int* __restrict__ rowptr3)
{
    __shared__ int sbuf[256];
    int b = blockIdx.y;
    int tid = threadIdx.x;
    int i = blockIdx.x * 256 + tid;
    int v = (i < NN) ? deg3[b * NN + i] : 0;
    sbuf[tid] = v;
    __syncthreads();
    for (int off = 1; off < 256; off <<= 1) {
        int t = (tid >= off) ? sbuf[tid - off] : 0;
        __syncthreads();
        sbuf[tid] += t;
        __syncthreads();
    }
    int base = parts[b * 256 + blockIdx.x];
    if (i < NN)      rowptr3[b * RPSTRIDE + i] = base + sbuf[tid] - v;
    if (i == NN - 1) rowptr3[b * RPSTRIDE + NN] = base + sbuf[tid];
}

// ---------- bucketed sort pass 0: init bucket heads from rowptr ----------
__global__ __launch_bounds__(256) void k_gheadinit(
    const int* __restrict__ rp3, int* __restrict__ ghead)
{
    int t = blockIdx.x * 256 + threadIdx.x;
    if (t < 3 * NBK) {
        int l = t / NBK, b = t % NBK;
        ghead[t] = rp3[l * RPSTRIDE + b * 256];
    }
}

// ---------- bucketed sort pass A: partition edges into dst-buckets ----------
__global__ __launch_bounds__(256) void k_bucketA(
    const int* __restrict__ src, const int* __restrict__ dst, const int* __restrict__ attr,
    int* __restrict__ ghead, unsigned int* __restrict__ ebuck3)
{
    __shared__ int hist[3 * NBK];
    __shared__ int head[3 * NBK];
    int tid = threadIdx.x;
    for (int i = tid; i < 3 * NBK; i += 256) hist[i] = 0;
    __syncthreads();
    int base_e = blockIdx.x * 4096;
    unsigned int word[16]; int bkt[16];
#pragma unroll
    for (int k = 0; k < 16; k++) {
        int e = base_e + k * 256 + tid;
        if (e < EE) {
            int d = dst[e], s = src[e], a = attr[e] + 1;
            int b = d >> 8;
            word[k] = (unsigned)s | ((unsigned)a << 16) | ((unsigned)(d & 255) << 18);
            bkt[k] = b;
            atomicAdd(&hist[2 * NBK + b], 1);
            if (a >= 1) atomicAdd(&hist[0 * NBK + b], 1);
            if (a <= 1) atomicAdd(&hist[1 * NBK + b], 1);
        } else { bkt[k] = -1; word[k] = 0; }
    }
    __syncthreads();
    for (int i = tid; i < 3 * NBK; i += 256) {
        int c = hist[i];
        head[i] = c ? atomicAdd(&ghead[i], c) : 0;
    }
    __syncthreads();
#pragma unroll
    for (int k = 0; k < 16; k++) {
        if (bkt[k] >= 0) {
            int b = bkt[k];
            unsigned int w = word[k];
            int a = (w >> 16) & 3;
            int p2 = atomicAdd(&head[2 * NBK + b], 1);
            ebuck3[2 * (size_t)EE + p2] = w;
            if (a >= 1) { int p0 = atomicAdd(&head[0 * NBK + b], 1); ebuck3[0 * (size_t)EE + p0] = w; }
            if (a <= 1) { int p1 = atomicAdd(&head[1 * NBK + b], 1); ebuck3[1 * (size_t)EE + p1] = w; }
        }
    }
}

// ---------- bucketed sort pass B: exact dst sort within bucket ----------
__global__ __launch_bounds__(256) void k_bucketB(
    const int* __restrict__ rp3, const unsigned int* __restrict__ ebuck3,
    int* __restrict__ sorted3)
{
    __shared__ int sbuf[256];
    __shared__ int head[256];
    int b = blockIdx.x, l = blockIdx.y, tid = threadIdx.x;
    int n0 = b * 256;
    int n1 = n0 + 256; if (n1 > NN) n1 = NN;
    int r0 = rp3[l * RPSTRIDE + n0];
    int r1 = rp3[l * RPSTRIDE + n1];
    const unsigned int* eb = ebuck3 + (size_t)l * EE;
    int* so = sorted3 + (size_t)l * EE;
    sbuf[tid] = 0;
    __syncthreads();
    for (int e = r0 + tid; e < r1; e += 256)
        atomicAdd(&sbuf[(eb[e] >> 18) & 255], 1);
    __syncthreads();
    int v = sbuf[tid];
    for (int off = 1; off < 256; off <<= 1) {
        int t = (tid >= off) ? sbuf[tid - off] : 0;
        __syncthreads();
        sbuf[tid] += t;
        __syncthreads();
    }
    head[tid] = r0 + sbuf[tid] - v;
    __syncthreads();
    for (int e = r0 + tid; e < r1; e += 256) {
        unsigned int w = eb[e];
        int pos = atomicAdd(&head[(w >> 18) & 255], 1);
        so[pos] = (int)(w & 0xFFFFu);
    }
}

// ---------- K2: h = relu(fold_bn01(x @ Wc')) ; MFMA split-bf16, split-K x2 ----------
// block = 4 waves = 2 tiles x 2 K-halves; x prefetch depth 1; LDS reduction
__global__ __launch_bounds__(256) void k_h(
    const float* __restrict__ x, const unsigned short* __restrict__ Whl,
    const float* __restrict__ WspP, const float* __restrict__ bias01,
    float* __restrict__ h)
{
    __shared__ float red[2][64][20];   // [tile-slot][lane][16 used, pad to 20]
    int wid = threadIdx.x >> 6, lane = threadIdx.x & 63;
    int slot = wid & 1;        // tile within block
    int khalf = wid >> 1;      // K half
    int tile = blockIdx.x * 2 + slot;
    bool active = (tile < 3125);           // 3125*16 == 50000
    int m = lane & 15, quad = lane >> 4;

    f32x4 c0 = {0.f,0.f,0.f,0.f}, c1 = c0, c2 = c0, c3 = c0;
    if (active) {
        const float* xr = x + (size_t)(tile * 16 + m) * 1028 + khalf * 512 + quad * 8;
        const unsigned short* Wh = Whl + khalf * 32768;
        const unsigned short* Wl = Whl + 65536 + khalf * 32768;
        f32x4 xa = *(const f32x4*)(xr);
        f32x4 xb = *(const f32x4*)(xr + 4);
        for (int i = 0; i < 16; i++) {
            f32x4 na = xa, nb = xb;
            if (i < 15) {                         // prefetch next x chunk (HBM)
                na = *(const f32x4*)(xr + (i + 1) * 32);
                nb = *(const f32x4*)(xr + (i + 1) * 32 + 4);
            }
            int fb = i * 2048 + lane * 8;
            bf16x8 bh0 = *(const bf16x8*)(Wh + fb);
            bf16x8 bh1 = *(const bf16x8*)(Wh + fb + 512);
            bf16x8 bh2 = *(const bf16x8*)(Wh + fb + 1024);
            bf16x8 bh3 = *(const bf16x8*)(Wh + fb + 1536);
            bf16x8 bl0 = *(const bf16x8*)(Wl + fb);
            bf16x8 bl1 = *(const bf16x8*)(Wl + fb + 512);
            bf16x8 bl2 = *(const bf16x8*)(Wl + fb + 1024);
            bf16x8 bl3 = *(const bf16x8*)(Wl + fb + 1536);
            bf16x8 xh, xl;
#pragma unroll
            for (int j = 0; j < 4; j++) {
                short hi, lo;
                split2(xa[j], hi, lo); xh[j] = hi; xl[j] = lo;
                split2(xb[j], hi, lo); xh[j + 4] = hi; xl[j + 4] = lo;
            }
            c0 = __builtin_amdgcn_mfma_f32_16x16x32_bf16(xh, bh0, c0, 0, 0, 0);
            c1 = __builtin_amdgcn_mfma_f32_16x16x32_bf16(xh, bh1, c1, 0, 0, 0);
            c2 = __builtin_amdgcn_mfma_f32_16x16x32_bf16(xh, bh2, c2, 0, 0, 0);
            c3 = __builtin_amdgcn_mfma_f32_16x16x32_bf16(xh, bh3, c3, 0, 0, 0);
            c0 = __builtin_amdgcn_mfma_f32_16x16x32_bf16(xl, bh0, c0, 0, 0, 0);
            c1 = __builtin_amdgcn_mfma_f32_16x16x32_bf16(xl, bh1, c1, 0, 0, 0);
            c2 = __builtin_amdgcn_mfma_f32_16x16x32_bf16(xl, bh2, c2, 0, 0, 0);
            c3 = __builtin_amdgcn_mfma_f32_16x16x32_bf16(xl, bh3, c3, 0, 0, 0);
            c0 = __builtin_amdgcn_mfma_f32_16x16x32_bf16(xh, bl0, c0, 0, 0, 0);
            c1 = __builtin_amdgcn_mfma_f32_16x16x32_bf16(xh, bl1, c1, 0, 0, 0);
            c2 = __builtin_amdgcn_mfma_f32_16x16x32_bf16(xh, bl2, c2, 0, 0, 0);
            c3 = __builtin_amdgcn_mfma_f32_16x16x32_bf16(xh, bl3, c3, 0, 0, 0);
            xa = na; xb = nb;
        }
    }
    if (khalf == 1 && active) {
        float* rp = &red[slot][lane][0];
        *(f32x4*)(rp)      = c0;
        *(f32x4*)(rp + 4)  = c1;
        *(f32x4*)(rp + 8)  = c2;
        *(f32x4*)(rp + 12) = c3;
    }
    __syncthreads();
    if (khalf == 0 && active) {
        const float* rp = &red[slot][lane][0];
        c0 += *(const f32x4*)(rp);
        c1 += *(const f32x4*)(rp + 4);
        c2 += *(const f32x4*)(rp + 8);
        c3 += *(const f32x4*)(rp + 12);
        f32x4 wsp[4]; float bia[4];
#pragma unroll
        for (int blk = 0; blk < 4; blk++) {
            int c = blk * 16 + m;
            wsp[blk] = *(const f32x4*)(WspP + c * 4);
            bia[blk] = bias01[c];
        }
#pragma unroll
        for (int r = 0; r < 4; r++) {
            int row = tile * 16 + quad * 4 + r;
            f32x4 sp = *(const f32x4*)(x + (size_t)row * 1028 + 1024);
            float cc[4] = { c0[r], c1[r], c2[r], c3[r] };
            float* hrow = h + (size_t)row * 64;
#pragma unroll
            for (int blk = 0; blk < 4; blk++) {
                float a = cc[blk] + sp[0] * wsp[blk][0] + sp[1] * wsp[blk][1]
                        + sp[2] * wsp[blk][2] + sp[3] * wsp[blk][3] + bia[blk];
                hrow[blk * 16 + m] = fmaxf(a, 0.f);
            }
        }
    }
}

// ---------- K4: PQ = h @ W1pq' (+b1 on P half) ----------
__global__ __launch_bounds__(256) void k_pq(
    const float* __restrict__ h, const float* __restrict__ WT,
    const float* __restrict__ biasPQ, float* __restrict__ PQ)
{
    __shared__ float wt[64 * 128];
    __shared__ float xt[64 * 68];
    int tid = threadIdx.x;
    int m0 = blockIdx.x * 64;
    int cg = tid & 31, rg = tid >> 5;
#pragma unroll
    for (int i = 0; i < 8; i++)
        ((float4*)wt)[i * 256 + tid] = ((const float4*)WT)[i * 256 + tid];
#pragma unroll
    for (int i = 0; i < 4; i++) {
        int li = i * 256 + tid;
        int rr = li >> 4, q = li & 15;
        int row = m0 + rr;
        float4 u = make_float4(0.f, 0.f, 0.f, 0.f);
        if (row < NN) u = *(const float4*)(h + (size_t)row * 64 + q * 4);
        *(float4*)(xt + rr * 68 + q * 4) = u;
    }
    __syncthreads();
    float acc[8][4];
#pragma unroll
    for (int r = 0; r < 8; r++)
#pragma unroll
        for (int j = 0; j < 4; j++) acc[r][j] = 0.f;
#pragma unroll 8
    for (int k = 0; k < 64; k++) {
        float4 wv = *(const float4*)(wt + k * 128 + cg * 4);
#pragma unroll
        for (int r = 0; r < 8; r++) {
            float xv = xt[(rg * 8 + r) * 68 + k];
            acc[r][0] += xv * wv.x; acc[r][1] += xv * wv.y;
            acc[r][2] += xv * wv.z; acc[r][3] += xv * wv.w;
        }
    }
#pragma unroll
    for (int r = 0; r < 8; r++) {
        int row = m0 + rg * 8 + r;
        if (row < NN) {
            float4 res;
            float* rp = &res.x;
#pragma unroll
            for (int j = 0; j < 4; j++)
                rp[j] = acc[r][j] + biasPQ[cg * 4 + j];
            *(float4*)(PQ + (size_t)row * 128 + cg * 4) = res;
        }
    }
}

// ---------- K5: EdgeConv via MFMA; one node per wave, 16 edges per batch ----------
__global__ __launch_bounds__(256) void k_edgeconv(
    const int* __restrict__ rowptr, const int* __restrict__ sorted,
    const float* __restrict__ PQ, const unsigned short* __restrict__ W2bf,
    const float* __restrict__ sc, float* __restrict__ y1, float* __restrict__ invcnt)
{
    int wid = threadIdx.x >> 6, lane = threadIdx.x & 63;
    int v = blockIdx.x * 4 + wid;
    if (v >= NN) return;
    int m = lane & 15, quad = lane >> 4;

    bf16x8 wfrag[4][2];
#pragma unroll
    for (int blk = 0; blk < 4; blk++)
#pragma unroll
        for (int kc = 0; kc < 2; kc++)
            wfrag[blk][kc] = *(const bf16x8*)(W2bf + (blk * 16 + m) * 64 + kc * 32 + quad * 8);

    const float* pr = PQ + (size_t)v * 128;
    f32x4 p00 = *(const f32x4*)(pr + quad * 8);
    f32x4 p01 = *(const f32x4*)(pr + quad * 8 + 4);
    f32x4 p10 = *(const f32x4*)(pr + 32 + quad * 8);
    f32x4 p11 = *(const f32x4*)(pr + 32 + quad * 8 + 4);

    int e0 = rowptr[v], e1 = rowptr[v + 1];
    int deg = e1 - e0;
    float acc[4][4];
#pragma unroll
    for (int blk = 0; blk < 4; blk++)
#pragma unroll
        for (int r = 0; r < 4; r++) acc[blk][r] = -3.0e38f;

    int nb = (deg + 15) >> 4;
    for (int bi = 0; bi < nb; bi++) {
        int e = e0 + bi * 16 + m;
        int srcm = (e < e1) ? sorted[e] : v;
        const float* qr = PQ + (size_t)srcm * 128 + 64;
        f32x4 q00 = *(const f32x4*)(qr + quad * 8);
        f32x4 q01 = *(const f32x4*)(qr + quad * 8 + 4);
        f32x4 q10 = *(const f32x4*)(qr + 32 + quad * 8);
        f32x4 q11 = *(const f32x4*)(qr + 32 + quad * 8 + 4);
        bf16x8 a0, a1;
#pragma unroll
        for (int j = 0; j < 4; j++) {
            a0[j]     = (short)f2bf(fmaxf(p00[j] + q00[j], 0.f));
            a0[j + 4] = (short)f2bf(fmaxf(p01[j] + q01[j], 0.f));
            a1[j]     = (short)f2bf(fmaxf(p10[j] + q10[j], 0.f));
            a1[j + 4] = (short)f2bf(fmaxf(p11[j] + q11[j], 0.f));
        }
        int rbase = bi * 16 + quad * 4;
#pragma unroll
        for (int blk = 0; blk < 4; blk++) {
            f32x4 c = { 0.f, 0.f, 0.f, 0.f };
            c = __builtin_amdgcn_mfma_f32_16x16x32_bf16(a0, wfrag[blk][0], c, 0, 0, 0);
            c = __builtin_amdgcn_mfma_f32_16x16x32_bf16(a1, wfrag[blk][1], c, 0, 0, 0);
#pragma unroll
            for (int r = 0; r < 4; r++) {
                float cv = (rbase + r < deg) ? c[r] : -3.0e38f;
                acc[blk][r] = fmaxf(acc[blk][r], cv);
            }
        }
    }
    float red[4];
#pragma unroll
    for (int blk = 0; blk < 4; blk++) {
        float rv = fmaxf(fmaxf(acc[blk][0], acc[blk][1]), fmaxf(acc[blk][2], acc[blk][3]));
        rv = fmaxf(rv, __shfl_xor(rv, 16));
        rv = fmaxf(rv, __shfl_xor(rv, 32));
        red[blk] = rv;
    }
    float mx = red[quad];
    float outv = (deg > 0) ? fmaxf(fmaf(mx, sc[lane], sc[64 + lane]), 0.f)
                           : fmaxf(sc[128 + lane], 0.f);
    y1[(size_t)v * 64 + lane] = outv;
    if (lane == 0) invcnt[v] = 1.0f / (float)(deg > 0 ? deg : 1);
}

// ---------- K6a: agg[v] = mean of y1[src]; 4-way unrolled ----------
__global__ __launch_bounds__(256) void k_agg(
    const int* __restrict__ rowptr, const int* __restrict__ sorted,
    const float* __restrict__ y1, const float* __restrict__ invcnt,
    float* __restrict__ agg)
{
    int wid = threadIdx.x >> 6, lane = threadIdx.x & 63;
    int v = blockIdx.x * 4 + wid;
    if (v >= NN) return;
    int e0 = rowptr[v], e1 = rowptr[v + 1];
    float a0 = 0.f, a1 = 0.f, a2 = 0.f, a3 = 0.f;
    int e = e0;
    for (; e + 4 <= e1; e += 4) {
        int s0 = sorted[e], s1 = sorted[e + 1], s2 = sorted[e + 2], s3 = sorted[e + 3];
        a0 += y1[(size_t)s0 * 64 + lane];
        a1 += y1[(size_t)s1 * 64 + lane];
        a2 += y1[(size_t)s2 * 64 + lane];
        a3 += y1[(size_t)s3 * 64 + lane];
    }
    for (; e < e1; e++) a0 += y1[(size_t)sorted[e] * 64 + lane];
    agg[(size_t)v * 64 + lane] = (a0 + a1 + a2 + a3) * invcnt[v];
}

// ---------- K6b: y2 = relu(fold_bn21([agg|y1] @ Wsage')) ----------
__global__ __launch_bounds__(256) void k_sage1(
    const float* __restrict__ aggp, const float* __restrict__ y1,
    const float* __restrict__ WsageT, const float* __restrict__ bias21,
    float* __restrict__ y2)
{
    __shared__ float wt[64 * 64];
    __shared__ float xt[128 * 68];
    int tid = threadIdx.x;
    int m0 = blockIdx.x * 128;
    int cg = tid & 15, rg = tid >> 4;
    float acc[8][4];
#pragma unroll
    for (int r = 0; r < 8; r++)
#pragma unroll
        for (int j = 0; j < 4; j++) acc[r][j] = 0.f;
    for (int ch = 0; ch < 2; ch++) {
        const float* A = ch ? y1 : aggp;
        __syncthreads();
#pragma unroll
        for (int i = 0; i < 4; i++)
            ((float4*)wt)[i * 256 + tid] = ((const float4*)(WsageT + ch * 4096))[i * 256 + tid];
#pragma unroll
        for (int i = 0; i < 8; i++) {
            int li = i * 256 + tid;
            int rr = li >> 4, q = li & 15;
            int row = m0 + rr;
            float4 u = make_float4(0.f, 0.f, 0.f, 0.f);
            if (row < NN) u = *(const float4*)(A + (size_t)row * 64 + q * 4);
            *(float4*)(xt + rr * 68 + q * 4) = u;
        }
        __syncthreads();
#pragma unroll 8
        for (int k = 0; k < 64; k++) {
            float4 wv = *(const float4*)(wt + k * 64 + cg * 4);
#pragma unroll
            for (int r = 0; r < 8; r++) {
                float xv = xt[(rg * 8 + r) * 68 + k];
                acc[r][0] += xv * wv.x; acc[r][1] += xv * wv.y;
                acc[r][2] += xv * wv.z; acc[r][3] += xv * wv.w;
            }
        }
    }
#pragma unroll
    for (int r = 0; r < 8; r++) {
        int row = m0 + rg * 8 + r;
        if (row < NN) {
            float4 res;
            float* rp = &res.x;
#pragma unroll
            for (int j = 0; j < 4; j++)
                rp[j] = fmaxf(acc[r][j] + bias21[cg * 4 + j], 0.f);
            *(float4*)(y2 + (size_t)row * 64 + cg * 4) = res;
        }
    }
}

// ---------- K7: per-node scalars p = y2.Wl3, z = y2.Wr3 + bl3 ----------
__global__ __launch_bounds__(256) void k_proj(
    const float* __restrict__ y2,
    const float* __restrict__ Wl3, const float* __restrict__ bl3,
    const float* __restrict__ Wr3,
    float* __restrict__ pbuf, float* __restrict__ zbuf)
{
    __shared__ float wl[64], wr[64];
    int tid = threadIdx.x;
    if (tid < 64) { wl[tid] = Wl3[tid]; wr[tid] = Wr3[tid]; }
    __syncthreads();
    int t = blockIdx.x * 256 + tid;
    if (t >= NN) return;
    const float* row = y2 + (size_t)t * 64;
    float ap = 0.f, az = 0.f;
#pragma unroll
    for (int j = 0; j < 16; j++) {
        float4 u = *(const float4*)(row + j * 4);
        const float* wlp = wl + j * 4;
        const float* wrp = wr + j * 4;
        ap += u.x * wlp[0] + u.y * wlp[1] + u.z * wlp[2] + u.w * wlp[3];
        az += u.x * wrp[0] + u.y * wrp[1] + u.z * wrp[2] + u.w * wrp[3];
    }
    pbuf[t] = ap;
    zbuf[t] = az + bl3[0];
}

// ---------- K8: o[v] += mean(p[src]) + z[v] ----------
__global__ __launch_bounds__(256) void k_sage2(
    const int* __restrict__ rowptr, const int* __restrict__ sorted,
    const float* __restrict__ pbuf, const float* __restrict__ zbuf,
    const float* __restrict__ invcnt, float* __restrict__ o)
{
    int wid = threadIdx.x >> 6, lane = threadIdx.x & 63;
    int v = blockIdx.x * 4 + wid;
    if (v >= NN) return;
    int e0 = rowptr[v], e1 = rowptr[v + 1];
    float s = 0.f;
    for (int e = e0 + lane; e < e1; e += 64) s += pbuf[sorted[e]];
#pragma unroll
    for (int off = 32; off > 0; off >>= 1) s += __shfl_xor(s, off);
    if (lane == 0) o[v] += s * invcnt[v] + zbuf[v];
}

// ---------- K9: sigmoid ----------
__global__ __launch_bounds__(256) void k_sigmoid(const float* __restrict__ o,
                                                 float* __restrict__ out)
{
    int t = blockIdx.x * 256 + threadIdx.x;
    if (t >= NN) return;
    out[t] = 1.f / (1.f + expf(-o[t]));
}

// ---------- launch ----------
extern "C" void kernel_launch(void* const* d_in, const int* in_sizes, int n_in,
                              void* d_out, int out_size, void* d_ws, size_t ws_size,
                              hipStream_t stream)
{
    const float* x    = (const float*)d_in[0];
    const int* ei     = (const int*)d_in[1];
    const int* attr   = (const int*)d_in[2];
    const float* Wspf = (const float*)d_in[3];
    const float* bspf = (const float*)d_in[4];
    const float* W011 = (const float*)d_in[5];
    const float* b011 = (const float*)d_in[6];
    const float* W012 = (const float*)d_in[7];
    const float* b012 = (const float*)d_in[8];
    const float* bn01 = (const float*)d_in[9];
    const float* eW1[3] = { (const float*)d_in[10], (const float*)d_in[15], (const float*)d_in[20] };
    const float* eb1[3] = { (const float*)d_in[11], (const float*)d_in[16], (const float*)d_in[21] };
    const float* eW2[3] = { (const float*)d_in[12], (const float*)d_in[17], (const float*)d_in[22] };
    const float* eb2[3] = { (const float*)d_in[13], (const float*)d_in[18], (const float*)d_in[23] };
    const float* bn1[3] = { (const float*)d_in[14], (const float*)d_in[19], (const float*)d_in[24] };
    const float* s21Wl = (const float*)d_in[25];
    const float* s21bl = (const float*)d_in[26];
    const float* s21Wr = (const float*)d_in[27];
    const float* bn21  = (const float*)d_in[28];
    const float* s3Wl[3] = { (const float*)d_in[29], (const float*)d_in[32], (const float*)d_in[35] };
    const float* s3bl[3] = { (const float*)d_in[30], (const float*)d_in[33], (const float*)d_in[36] };
    const float* s3Wr[3] = { (const float*)d_in[31], (const float*)d_in[34], (const float*)d_in[37] };

    char* ws = (char*)d_ws;
    unsigned short* Whl = (unsigned short*)(ws + OFF_WHL);
    float* WspP   = (float*)(ws + OFF_WSPP);
    float* bias01 = (float*)(ws + OFF_BIAS01);
    float* W1pqT  = (float*)(ws + OFF_W1PQT);
    float* biasPQ = (float*)(ws + OFF_BIASPQ);
    float* WsageT = (float*)(ws + OFF_WSAGET);
    float* bias21 = (float*)(ws + OFF_BIAS21);
    float* bnf    = (float*)(ws + OFF_BNF);
    unsigned short* W2bf = (unsigned short*)(ws + OFF_W2BF);
    float* invcnt = (float*)(ws + OFF_INVCNT);
    float* pbuf   = (float*)(ws + OFF_PBUF);
    float* zbuf   = (float*)(ws + OFF_ZBUF);
    int*   rp3    = (int*)(ws + OFF_RP3);
    int*   parts  = (int*)(ws + OFF_PARTS);
    int*   deg3   = (int*)(ws + OFF_DEG3);
    int*   ghead  = (int*)(ws + OFF_GHEAD);
    float* o      = (float*)(ws + OFF_O);
    int*   sort3  = (int*)(ws + OFF_SORT3);
    unsigned int* ebuck3 = (unsigned int*)(ws + OFF_EBUCK3);
    float* h      = (float*)(ws + OFF_H);
    float* PQ     = (float*)(ws + OFF_PQ);
    float* y1     = (float*)(ws + OFF_Y1);
    float* aggp   = (float*)(ws + OFF_AGG);
    float* y2     = (float*)(ws + OFF_Y2);   // overlays PQ (dead by then)

    hipMemsetAsync(ws + OFF_DEG3, 0, 1400000, stream);

    k_prep<<<689, 256, 0, stream>>>(
        Wspf, bspf, W011, b011, W012, b012, bn01,
        eW1[0], eb1[0], eb2[0], bn1[0],
        eW1[1], eb1[1], eb2[1], bn1[1],
        eW1[2], eb1[2], eb2[2], bn1[2],
        eW2[0], eW2[1], eW2[2],
        s21Wl, s21bl, s21Wr, bn21,
        Whl, WspP, bias01, W1pqT, biasPQ, WsageT, bias21, bnf, W2bf);

    k_hist3<<<3907, 256, 0, stream>>>(ei + EE, attr, deg3);
    k_psum<<<dim3(196, 3), 256, 0, stream>>>(deg3, parts);
    k_pscan<<<1, 256, 0, stream>>>(parts);
    k_scanfix<<<dim3(196, 3), 256, 0, stream>>>(deg3, parts, rp3);
    k_gheadinit<<<3, 256, 0, stream>>>(rp3, ghead);
    k_bucketA<<<245, 256, 0, stream>>>(ei, ei + EE, attr, ghead, ebuck3);
    k_bucketB<<<dim3(NBK, 3), 256, 0, stream>>>(rp3, ebuck3, sort3);

    k_h<<<1563, 256, 0, stream>>>(x, Whl, WspP, bias01, h);

    for (int b = 0; b < 3; b++) {
        const int* rp = rp3 + b * RPSTRIDE;
        const int* so = sort3 + (size_t)b * EE;
        k_pq<<<782, 256, 0, stream>>>(h, W1pqT + b * 8192, biasPQ + b * 128, PQ);
        k_edgeconv<<<12500, 256, 0, stream>>>(rp, so, PQ, W2bf + b * 4096,
                                              bnf + b * 192, y1, invcnt);
        k_agg<<<12500, 256, 0, stream>>>(rp, so, y1, invcnt, aggp);
        k_sage1<<<391, 256, 0, stream>>>(aggp, y1, WsageT, bias21, y2);
        k_proj<<<196, 256, 0, stream>>>(y2, s3Wl[b], s3bl[b], s3Wr[b], pbuf, zbuf);
        k_sage2<<<12500, 256, 0, stream>>>(rp, so, pbuf, zbuf, invcnt, o);
    }
    k_sigmoid<<<196, 256, 0, stream>>>(o, (float*)d_out);
}

// Round 7
// 1071.035 us; speedup vs baseline: 1.0237x; 1.0237x over previous
//
#include <hip/hip_runtime.h>
#include <cstdint>
#include <cstddef>

#define NN 50000
#define EE 1000000
#define RPSTRIDE 50016   // rowptr stride per branch (ints)
#define NBK 196          // dst buckets (dst>>8), 196*256 = 50176 >= NN

typedef __attribute__((ext_vector_type(8))) short bf16x8;
typedef __attribute__((ext_vector_type(4))) short s16x4;
typedef __attribute__((ext_vector_type(4))) float f32x4;

__device__ __forceinline__ unsigned short f2bf(float f) {
    union { unsigned int i; float f; } v; v.f = f;
    unsigned int u = v.i;
    u = u + 0x7FFFu + ((u >> 16) & 1u);
    return (unsigned short)(u >> 16);
}

// truncation split: v == bf16(hi) + ~bf16(lo), residual ~2^-16 rel
__device__ __forceinline__ void split2(float v, short& hi, short& lo) {
    union { float f; unsigned int u; } a; a.f = v;
    unsigned short h16 = (unsigned short)(a.u >> 16);
    union { unsigned int u; float f; } hf; hf.u = ((unsigned int)h16) << 16;
    union { float f; unsigned int u; } b; b.f = v - hf.f;
    hi = (short)h16;
    lo = (short)(b.u >> 16);
}

// ---------- workspace layout (byte offsets) ----------
#define OFF_WHL    ((size_t)0)         // 2*1024*64 bf16 (hi|lo, frag-packed) = 262144
#define OFF_WSPP   ((size_t)262144)    // 64*4 f32
#define OFF_BIAS01 ((size_t)263168)    // 64 f32
#define OFF_W1PQT  ((size_t)263424)    // 3*64*128 f32
#define OFF_BIASPQ ((size_t)361728)    // 3*128 f32
#define OFF_WSAGET ((size_t)363264)    // 128*64 f32
#define OFF_BIAS21 ((size_t)396032)    // 64 f32
#define OFF_BNF    ((size_t)396288)    // 3*192 f32 (+pad to 2560)
#define OFF_W2BF   ((size_t)398848)    // 3*64*64 bf16 = 24576
#define OFF_INVCNT ((size_t)423424)    // N f32
#define OFF_PBUF   ((size_t)623424)    // N f32
#define OFF_ZBUF   ((size_t)823424)    // N f32
#define OFF_RP3    ((size_t)1023424)   // 3*RPSTRIDE i32 = 600192
#define OFF_PARTS  ((size_t)1623616)   // 3*256 i32 (+pad 4096)
#define OFF_DEG3   ((size_t)1627712)   // 3*N i32 = 600000
#define OFF_GHEAD  ((size_t)2227712)   // 3*NBK i32 (+pad 600000)
#define OFF_O      ((size_t)2827712)   // N f32   = 200000
#define OFF_SORT3  ((size_t)3027712)   // 3*E i32 = 12000000
#define OFF_H      ((size_t)15027712)  // N*64 f32 = 12800000
#define OFF_PQ     ((size_t)27827712)  // N*128 f32 = 25600000
#define OFF_Y1     ((size_t)53427712)  // N*64 f32
#define OFF_AGG    ((size_t)66227712)  // N*64 f32 (end 79027712)
#define OFF_Y2     OFF_PQ              // overlay: PQ dead after edgeconv
#define OFF_EBUCK3 OFF_Y1              // overlay: 3*E u32, dead before edgeconv

// ---------- K1: weight prep / folding ----------
__global__ __launch_bounds__(256) void k_prep(
    const float* __restrict__ Wspf, const float* __restrict__ bspf,
    const float* __restrict__ W011, const float* __restrict__ b011,
    const float* __restrict__ W012, const float* __restrict__ b012,
    const float* __restrict__ bn01,
    const float* __restrict__ e1W1, const float* __restrict__ e1b1,
    const float* __restrict__ e1b2, const float* __restrict__ bn11,
    const float* __restrict__ e2W1, const float* __restrict__ e2b1,
    const float* __restrict__ e2b2, const float* __restrict__ bn12,
    const float* __restrict__ e3W1, const float* __restrict__ e3b1,
    const float* __restrict__ e3b2, const float* __restrict__ bn13,
    const float* __restrict__ e1W2, const float* __restrict__ e2W2,
    const float* __restrict__ e3W2,
    const float* __restrict__ s21Wl, const float* __restrict__ s21bl,
    const float* __restrict__ s21Wr, const float* __restrict__ bn21,
    unsigned short* __restrict__ Whl, float* __restrict__ WspP, float* __restrict__ bias01,
    float* __restrict__ W1pqT, float* __restrict__ biasPQ,
    float* __restrict__ WsageT, float* __restrict__ bias21, float* __restrict__ bnf,
    unsigned short* __restrict__ W2bf)
{
    int idx = blockIdx.x * 256 + threadIdx.x;
    if (idx < 131072) {
        int hl = idx >> 16;
        int r = idx & 65535;
        int kchunk = r >> 11;
        int r2 = r & 2047;
        int blk = r2 >> 9;
        int r3 = r2 & 511;
        int lane = r3 >> 3;
        int j = r3 & 7;
        int n = lane & 15, quad = lane >> 4;
        int k = kchunk * 32 + quad * 8 + j;
        int c = blk * 16 + n;
        float s = bn01[c] * rsqrtf(bn01[192 + c] + 1e-5f);
        float w = ((k < 512) ? W012[c * 512 + k] : W011[c * 576 + (k - 512)]) * s;
        short hi, lo;
        split2(w, hi, lo);
        Whl[idx] = (unsigned short)(hl ? lo : hi);
    } else if (idx < 131072 + 24576) {
        int r = idx - 131072;
        int b = r >> 13; r &= 8191;
        int k = r >> 7, cp = r & 127;
        const float* W1 = (b == 0) ? e1W1 : (b == 1) ? e2W1 : e3W1;
        float val;
        if (cp < 64) val = W1[cp * 128 + k] - W1[cp * 128 + 64 + k];
        else         val = W1[(cp - 64) * 128 + 64 + k];
        W1pqT[b * 8192 + k * 128 + cp] = val;
    } else if (idx < 131072 + 24576 + 8192) {
        int r = idx - (131072 + 24576);
        int k = r >> 6, c = r & 63;
        float s = bn21[c] * rsqrtf(bn21[192 + c] + 1e-5f);
        float w = (k < 64) ? s21Wl[c * 64 + k] : s21Wr[c * 64 + (k - 64)];
        WsageT[k * 64 + c] = w * s;
    } else if (idx < 131072 + 24576 + 8192 + 64) {
        int c = idx - (131072 + 24576 + 8192);
        float s01 = bn01[c] * rsqrtf(bn01[192 + c] + 1e-5f);
        float wsp0 = 0.f, wsp1 = 0.f, wsp2 = 0.f, wsp3 = 0.f, bacc = 0.f;
        for (int j = 0; j < 64; j++) {
            float w = W011[c * 576 + 512 + j];
            wsp0 += w * Wspf[j * 4 + 0];
            wsp1 += w * Wspf[j * 4 + 1];
            wsp2 += w * Wspf[j * 4 + 2];
            wsp3 += w * Wspf[j * 4 + 3];
            bacc += w * bspf[j];
        }
        WspP[c * 4 + 0] = wsp0 * s01; WspP[c * 4 + 1] = wsp1 * s01;
        WspP[c * 4 + 2] = wsp2 * s01; WspP[c * 4 + 3] = wsp3 * s01;
        bias01[c] = (b011[c] + b012[c] + bacc) * s01 + (bn01[64 + c] - bn01[128 + c] * s01);
        float s21 = bn21[c] * rsqrtf(bn21[192 + c] + 1e-5f);
        bias21[c] = s21bl[c] * s21 + (bn21[64 + c] - bn21[128 + c] * s21);
        const float* b1a[3] = { e1b1, e2b1, e3b1 };
        const float* b2a[3] = { e1b2, e2b2, e3b2 };
        const float* bna[3] = { bn11, bn12, bn13 };
#pragma unroll
        for (int b = 0; b < 3; b++) {
            float s = bna[b][c] * rsqrtf(bna[b][192 + c] + 1e-5f);
            float tr = bna[b][64 + c] - bna[b][128 + c] * s;
            bnf[b * 192 + c] = s;
            bnf[b * 192 + 64 + c] = b2a[b][c] * s + tr;
            bnf[b * 192 + 128 + c] = tr;
            biasPQ[b * 128 + c] = b1a[b][c];
            biasPQ[b * 128 + 64 + c] = 0.f;
        }
    } else if (idx < 131072 + 24576 + 8192 + 64 + 12288) {
        int r = idx - (131072 + 24576 + 8192 + 64);
        int b = r >> 12, i = r & 4095;
        const float* W2 = (b == 0) ? e1W2 : (b == 1) ? e2W2 : e3W2;
        W2bf[b * 4096 + i] = f2bf(W2[i]);
    }
}

// ---------- per-branch degree histogram ----------
__global__ __launch_bounds__(256) void k_hist3(
    const int* __restrict__ dst, const int* __restrict__ attr, int* __restrict__ deg3)
{
    int e = blockIdx.x * 256 + threadIdx.x;
    if (e < EE) {
        int d = dst[e], a = attr[e];
        atomicAdd(&deg3[2 * NN + d], 1);
        if (a >= 0) atomicAdd(&deg3[0 * NN + d], 1);
        if (a <= 0) atomicAdd(&deg3[1 * NN + d], 1);
    }
}

__global__ __launch_bounds__(256) void k_psum(const int* __restrict__ deg3, int* __restrict__ parts)
{
    int b = blockIdx.y;
    int i = blockIdx.x * 256 + threadIdx.x;
    int v = (i < NN) ? deg3[b * NN + i] : 0;
#pragma unroll
    for (int off = 32; off > 0; off >>= 1) v += __shfl_xor(v, off);
    __shared__ int ws4[4];
    int wid = threadIdx.x >> 6;
    if ((threadIdx.x & 63) == 0) ws4[wid] = v;
    __syncthreads();
    if (threadIdx.x == 0)
        parts[b * 256 + blockIdx.x] = ws4[0] + ws4[1] + ws4[2] + ws4[3];
}

__global__ __launch_bounds__(256) void k_pscan(int* __restrict__ parts)
{
    __shared__ int sbuf[256];
    int tid = threadIdx.x;
    for (int b = 0; b < 3; b++) {
        int v = (tid < 196) ? parts[b * 256 + tid] : 0;
        sbuf[tid] = v;
        __syncthreads();
        for (int off = 1; off < 256; off <<= 1) {
            int t = (tid >= off) ? sbuf[tid - off] : 0;
            __syncthreads();
            sbuf[tid] += t;
            __syncthreads();
        }
        if (tid < 196) parts[b * 256 + tid] = sbuf[tid] - v;  // exclusive
        __syncthreads();
    }
}

__global__ __launch_bounds__(256) void k_scanfix(
    const int* __restrict__ deg3, const int* __restrict__ parts, int* __restrict__ rowptr3)
{
    __shared__ int sbuf[256];
    int b = blockIdx.y;
    int tid = threadIdx.x;
    int i = blockIdx.x * 256 + tid;
    int v = (i < NN) ? deg3[b * NN + i] : 0;
    sbuf[tid] = v;
    __syncthreads();
    for (int off = 1; off < 256; off <<= 1) {
        int t = (tid >= off) ? sbuf[tid - off] : 0;
        __syncthreads();
        sbuf[tid] += t;
        __syncthreads();
    }
    int base = parts[b * 256 + blockIdx.x];
    if (i < NN)      rowptr3[b * RPSTRIDE + i] = base + sbuf[tid] - v;
    if (i == NN - 1) rowptr3[b * RPSTRIDE + NN] = base + sbuf[tid];
}

// ---------- bucketed sort pass 0: init bucket heads from rowptr ----------
__global__ __launch_bounds__(256) void k_gheadinit(
    const int* __restrict__ rp3, int* __restrict__ ghead)
{
    int t = blockIdx.x * 256 + threadIdx.x;
    if (t < 3 * NBK) {
        int l = t / NBK, b = t % NBK;
        ghead[t] = rp3[l * RPSTRIDE + b * 256];
    }
}

// ---------- bucketed sort pass A: partition edges into dst-buckets ----------
__global__ __launch_bounds__(256) void k_bucketA(
    const int* __restrict__ src, const int* __restrict__ dst, const int* __restrict__ attr,
    int* __restrict__ ghead, unsigned int* __restrict__ ebuck3)
{
    __shared__ int hist[3 * NBK];
    __shared__ int head[3 * NBK];
    int tid = threadIdx.x;
    for (int i = tid; i < 3 * NBK; i += 256) hist[i] = 0;
    __syncthreads();
    int base_e = blockIdx.x * 4096;
    unsigned int word[16]; int bkt[16];
#pragma unroll
    for (int k = 0; k < 16; k++) {
        int e = base_e + k * 256 + tid;
        if (e < EE) {
            int d = dst[e], s = src[e], a = attr[e] + 1;
            int b = d >> 8;
            word[k] = (unsigned)s | ((unsigned)a << 16) | ((unsigned)(d & 255) << 18);
            bkt[k] = b;
            atomicAdd(&hist[2 * NBK + b], 1);
            if (a >= 1) atomicAdd(&hist[0 * NBK + b], 1);
            if (a <= 1) atomicAdd(&hist[1 * NBK + b], 1);
        } else { bkt[k] = -1; word[k] = 0; }
    }
    __syncthreads();
    for (int i = tid; i < 3 * NBK; i += 256) {
        int c = hist[i];
        head[i] = c ? atomicAdd(&ghead[i], c) : 0;
    }
    __syncthreads();
#pragma unroll
    for (int k = 0; k < 16; k++) {
        if (bkt[k] >= 0) {
            int b = bkt[k];
            unsigned int w = word[k];
            int a = (w >> 16) & 3;
            int p2 = atomicAdd(&head[2 * NBK + b], 1);
            ebuck3[2 * (size_t)EE + p2] = w;
            if (a >= 1) { int p0 = atomicAdd(&head[0 * NBK + b], 1); ebuck3[0 * (size_t)EE + p0] = w; }
            if (a <= 1) { int p1 = atomicAdd(&head[1 * NBK + b], 1); ebuck3[1 * (size_t)EE + p1] = w; }
        }
    }
}

// ---------- bucketed sort pass B: exact dst sort within bucket ----------
__global__ __launch_bounds__(256) void k_bucketB(
    const int* __restrict__ rp3, const unsigned int* __restrict__ ebuck3,
    int* __restrict__ sorted3)
{
    __shared__ int sbuf[256];
    __shared__ int head[256];
    int b = blockIdx.x, l = blockIdx.y, tid = threadIdx.x;
    int n0 = b * 256;
    int n1 = n0 + 256; if (n1 > NN) n1 = NN;
    int r0 = rp3[l * RPSTRIDE + n0];
    int r1 = rp3[l * RPSTRIDE + n1];
    const unsigned int* eb = ebuck3 + (size_t)l * EE;
    int* so = sorted3 + (size_t)l * EE;
    sbuf[tid] = 0;
    __syncthreads();
    for (int e = r0 + tid; e < r1; e += 256)
        atomicAdd(&sbuf[(eb[e] >> 18) & 255], 1);
    __syncthreads();
    int v = sbuf[tid];
    for (int off = 1; off < 256; off <<= 1) {
        int t = (tid >= off) ? sbuf[tid - off] : 0;
        __syncthreads();
        sbuf[tid] += t;
        __syncthreads();
    }
    head[tid] = r0 + sbuf[tid] - v;
    __syncthreads();
    for (int e = r0 + tid; e < r1; e += 256) {
        unsigned int w = eb[e];
        int pos = atomicAdd(&head[(w >> 18) & 255], 1);
        so[pos] = (int)(w & 0xFFFFu);
    }
}

// ---------- K2: h = relu(fold_bn01(x @ Wc')) ; LDS-staged contiguous stream ----------
// block = one 16-row tile; 4 waves split 64 output cols; x staged via LDS in
// 256-float K-chunks with 1KB-contiguous wave reads (DRAM-friendly), split to
// bf16 hi/lo once, stored XOR-swizzled for conflict-light ds_read_b128 A-frags.
__global__ __launch_bounds__(256) void k_h(
    const float* __restrict__ x, const unsigned short* __restrict__ Whl,
    const float* __restrict__ WspP, const float* __restrict__ bias01,
    float* __restrict__ h)
{
    __shared__ unsigned short hib[2][4096];   // [buf][m*256 + oct'*8 + j]
    __shared__ unsigned short lob[2][4096];
    int tid = threadIdx.x;
    int w = tid >> 6, l = tid & 63;
    int tile = blockIdx.x;                    // 3125 tiles * 16 rows = 50000
    int m = l & 15, quad = l >> 4;
    int blk = w;                              // this wave's 16-col block
    const unsigned short* Wh = Whl;
    const unsigned short* Wl = Whl + 65536;
    const size_t xbase = (size_t)tile * 16 * 1028;

    int oct_w = l >> 1, off_w = (l & 1) * 4;  // staging write positions

    // prologue: global-load chunk 0 (1KB contiguous per wave per pass)
    f32x4 g[4];
#pragma unroll
    for (int p = 0; p < 4; p++)
        g[p] = *(const f32x4*)(x + xbase + (size_t)(p * 4 + w) * 1028 + l * 4);
    // write chunk 0 into buf 0
#pragma unroll
    for (int p = 0; p < 4; p++) {
        int r = p * 4 + w;
        int op = r * 256 + (oct_w ^ (r & 7)) * 8 + off_w;
        s16x4 h4, l4;
#pragma unroll
        for (int i = 0; i < 4; i++) { short hi, lo; split2(g[p][i], hi, lo); h4[i] = hi; l4[i] = lo; }
        *(s16x4*)(&hib[0][op]) = h4;
        *(s16x4*)(&lob[0][op]) = l4;
    }
    __syncthreads();

    f32x4 acc = { 0.f, 0.f, 0.f, 0.f };
    for (int c = 0; c < 4; c++) {
        if (c < 3) {      // prefetch next chunk's globals (long-latency, overlapped)
#pragma unroll
            for (int p = 0; p < 4; p++)
                g[p] = *(const f32x4*)(x + xbase + (size_t)(p * 4 + w) * 1028 + (c + 1) * 256 + l * 4);
        }
        int buf = c & 1;
        const unsigned short* hp = &hib[buf][m * 256];
        const unsigned short* lp = &lob[buf][m * 256];
        int msw = m & 7;
#pragma unroll
        for (int ks = 0; ks < 8; ks++) {
            int oct = ks * 4 + quad;
            int ao = (oct ^ msw) * 8;
            bf16x8 xh = *(const bf16x8*)(hp + ao);
            bf16x8 xl = *(const bf16x8*)(lp + ao);
            int fb = (c * 8 + ks) * 2048 + blk * 512 + l * 8;
            bf16x8 bh = *(const bf16x8*)(Wh + fb);
            bf16x8 bl = *(const bf16x8*)(Wl + fb);
            acc = __builtin_amdgcn_mfma_f32_16x16x32_bf16(xh, bh, acc, 0, 0, 0);
            acc = __builtin_amdgcn_mfma_f32_16x16x32_bf16(xl, bh, acc, 0, 0, 0);
            acc = __builtin_amdgcn_mfma_f32_16x16x32_bf16(xh, bl, acc, 0, 0, 0);
        }
        if (c < 3) {
            int nbuf = (c + 1) & 1;
#pragma unroll
            for (int p = 0; p < 4; p++) {
                int r = p * 4 + w;
                int op = r * 256 + (oct_w ^ (r & 7)) * 8 + off_w;
                s16x4 h4, l4;
#pragma unroll
                for (int i = 0; i < 4; i++) { short hi, lo; split2(g[p][i], hi, lo); h4[i] = hi; l4[i] = lo; }
                *(s16x4*)(&hib[nbuf][op]) = h4;
                *(s16x4*)(&lob[nbuf][op]) = l4;
            }
            __syncthreads();
        }
    }

    // epilogue: C col = m (-> channel blk*16+m), row = quad*4+r
    int ch = blk * 16 + m;
    f32x4 wsp = *(const f32x4*)(WspP + ch * 4);
    float bia = bias01[ch];
#pragma unroll
    for (int r = 0; r < 4; r++) {
        int row = tile * 16 + quad * 4 + r;
        f32x4 sp = *(const f32x4*)(x + (size_t)row * 1028 + 1024);
        float a = acc[r] + sp[0] * wsp[0] + sp[1] * wsp[1]
                + sp[2] * wsp[2] + sp[3] * wsp[3] + bia;
        h[(size_t)row * 64 + ch] = fmaxf(a, 0.f);
    }
}

// ---------- K4: PQ = h @ W1pq' (+b1 on P half) ----------
__global__ __launch_bounds__(256) void k_pq(
    const float* __restrict__ h, const float* __restrict__ WT,
    const float* __restrict__ biasPQ, float* __restrict__ PQ)
{
    __shared__ float wt[64 * 128];
    __shared__ float xt[64 * 68];
    int tid = threadIdx.x;
    int m0 = blockIdx.x * 64;
    int cg = tid & 31, rg = tid >> 5;
#pragma unroll
    for (int i = 0; i < 8; i++)
        ((float4*)wt)[i * 256 + tid] = ((const float4*)WT)[i * 256 + tid];
#pragma unroll
    for (int i = 0; i < 4; i++) {
        int li = i * 256 + tid;
        int rr = li >> 4, q = li & 15;
        int row = m0 + rr;
        float4 u = make_float4(0.f, 0.f, 0.f, 0.f);
        if (row < NN) u = *(const float4*)(h + (size_t)row * 64 + q * 4);
        *(float4*)(xt + rr * 68 + q * 4) = u;
    }
    __syncthreads();
    float acc[8][4];
#pragma unroll
    for (int r = 0; r < 8; r++)
#pragma unroll
        for (int j = 0; j < 4; j++) acc[r][j] = 0.f;
#pragma unroll 8
    for (int k = 0; k < 64; k++) {
        float4 wv = *(const float4*)(wt + k * 128 + cg * 4);
#pragma unroll
        for (int r = 0; r < 8; r++) {
            float xv = xt[(rg * 8 + r) * 68 + k];
            acc[r][0] += xv * wv.x; acc[r][1] += xv * wv.y;
            acc[r][2] += xv * wv.z; acc[r][3] += xv * wv.w;
        }
    }
#pragma unroll
    for (int r = 0; r < 8; r++) {
        int row = m0 + rg * 8 + r;
        if (row < NN) {
            float4 res;
            float* rp = &res.x;
#pragma unroll
            for (int j = 0; j < 4; j++)
                rp[j] = acc[r][j] + biasPQ[cg * 4 + j];
            *(float4*)(PQ + (size_t)row * 128 + cg * 4) = res;
        }
    }
}

// ---------- K5: EdgeConv via MFMA; one node per wave, 16 edges per batch ----------
__global__ __launch_bounds__(256) void k_edgeconv(
    const int* __restrict__ rowptr, const int* __restrict__ sorted,
    const float* __restrict__ PQ, const unsigned short* __restrict__ W2bf,
    const float* __restrict__ sc, float* __restrict__ y1, float* __restrict__ invcnt)
{
    int wid = threadIdx.x >> 6, lane = threadIdx.x & 63;
    int v = blockIdx.x * 4 + wid;
    if (v >= NN) return;
    int m = lane & 15, quad = lane >> 4;

    bf16x8 wfrag[4][2];
#pragma unroll
    for (int blk = 0; blk < 4; blk++)
#pragma unroll
        for (int kc = 0; kc < 2; kc++)
            wfrag[blk][kc] = *(const bf16x8*)(W2bf + (blk * 16 + m) * 64 + kc * 32 + quad * 8);

    const float* pr = PQ + (size_t)v * 128;
    f32x4 p00 = *(const f32x4*)(pr + quad * 8);
    f32x4 p01 = *(const f32x4*)(pr + quad * 8 + 4);
    f32x4 p10 = *(const f32x4*)(pr + 32 + quad * 8);
    f32x4 p11 = *(const f32x4*)(pr + 32 + quad * 8 + 4);

    int e0 = rowptr[v], e1 = rowptr[v + 1];
    int deg = e1 - e0;
    float acc[4][4];
#pragma unroll
    for (int blk = 0; blk < 4; blk++)
#pragma unroll
        for (int r = 0; r < 4; r++) acc[blk][r] = -3.0e38f;

    int nb = (deg + 15) >> 4;
    for (int bi = 0; bi < nb; bi++) {
        int e = e0 + bi * 16 + m;
        int srcm = (e < e1) ? sorted[e] : v;
        const float* qr = PQ + (size_t)srcm * 128 + 64;
        f32x4 q00 = *(const f32x4*)(qr + quad * 8);
        f32x4 q01 = *(const f32x4*)(qr + quad * 8 + 4);
        f32x4 q10 = *(const f32x4*)(qr + 32 + quad * 8);
        f32x4 q11 = *(const f32x4*)(qr + 32 + quad * 8 + 4);
        bf16x8 a0, a1;
#pragma unroll
        for (int j = 0; j < 4; j++) {
            a0[j]     = (short)f2bf(fmaxf(p00[j] + q00[j], 0.f));
            a0[j + 4] = (short)f2bf(fmaxf(p01[j] + q01[j], 0.f));
            a1[j]     = (short)f2bf(fmaxf(p10[j] + q10[j], 0.f));
            a1[j + 4] = (short)f2bf(fmaxf(p11[j] + q11[j], 0.f));
        }
        int rbase = bi * 16 + quad * 4;
#pragma unroll
        for (int blk = 0; blk < 4; blk++) {
            f32x4 c = { 0.f, 0.f, 0.f, 0.f };
            c = __builtin_amdgcn_mfma_f32_16x16x32_bf16(a0, wfrag[blk][0], c, 0, 0, 0);
            c = __builtin_amdgcn_mfma_f32_16x16x32_bf16(a1, wfrag[blk][1], c, 0, 0, 0);
#pragma unroll
            for (int r = 0; r < 4; r++) {
                float cv = (rbase + r < deg) ? c[r] : -3.0e38f;
                acc[blk][r] = fmaxf(acc[blk][r], cv);
            }
        }
    }
    float red[4];
#pragma unroll
    for (int blk = 0; blk < 4; blk++) {
        float rv = fmaxf(fmaxf(acc[blk][0], acc[blk][1]), fmaxf(acc[blk][2], acc[blk][3]));
        rv = fmaxf(rv, __shfl_xor(rv, 16));
        rv = fmaxf(rv, __shfl_xor(rv, 32));
        red[blk] = rv;
    }
    float mx = red[quad];
    float outv = (deg > 0) ? fmaxf(fmaf(mx, sc[lane], sc[64 + lane]), 0.f)
                           : fmaxf(sc[128 + lane], 0.f);
    y1[(size_t)v * 64 + lane] = outv;
    if (lane == 0) invcnt[v] = 1.0f / (float)(deg > 0 ? deg : 1);
}

// ---------- K6a: agg[v] = mean of y1[src]; 4-way unrolled ----------
__global__ __launch_bounds__(256) void k_agg(
    const int* __restrict__ rowptr, const int* __restrict__ sorted,
    const float* __restrict__ y1, const float* __restrict__ invcnt,
    float* __restrict__ agg)
{
    int wid = threadIdx.x >> 6, lane = threadIdx.x & 63;
    int v = blockIdx.x * 4 + wid;
    if (v >= NN) return;
    int e0 = rowptr[v], e1 = rowptr[v + 1];
    float a0 = 0.f, a1 = 0.f, a2 = 0.f, a3 = 0.f;
    int e = e0;
    for (; e + 4 <= e1; e += 4) {
        int s0 = sorted[e], s1 = sorted[e + 1], s2 = sorted[e + 2], s3 = sorted[e + 3];
        a0 += y1[(size_t)s0 * 64 + lane];
        a1 += y1[(size_t)s1 * 64 + lane];
        a2 += y1[(size_t)s2 * 64 + lane];
        a3 += y1[(size_t)s3 * 64 + lane];
    }
    for (; e < e1; e++) a0 += y1[(size_t)sorted[e] * 64 + lane];
    agg[(size_t)v * 64 + lane] = (a0 + a1 + a2 + a3) * invcnt[v];
}

// ---------- K6b: y2 = relu(fold_bn21([agg|y1] @ Wsage')) ----------
__global__ __launch_bounds__(256) void k_sage1(
    const float* __restrict__ aggp, const float* __restrict__ y1,
    const float* __restrict__ WsageT, const float* __restrict__ bias21,
    float* __restrict__ y2)
{
    __shared__ float wt[64 * 64];
    __shared__ float xt[128 * 68];
    int tid = threadIdx.x;
    int m0 = blockIdx.x * 128;
    int cg = tid & 15, rg = tid >> 4;
    float acc[8][4];
#pragma unroll
    for (int r = 0; r < 8; r++)
#pragma unroll
        for (int j = 0; j < 4; j++) acc[r][j] = 0.f;
    for (int ch = 0; ch < 2; ch++) {
        const float* A = ch ? y1 : aggp;
        __syncthreads();
#pragma unroll
        for (int i = 0; i < 4; i++)
            ((float4*)wt)[i * 256 + tid] = ((const float4*)(WsageT + ch * 4096))[i * 256 + tid];
#pragma unroll
        for (int i = 0; i < 8; i++) {
            int li = i * 256 + tid;
            int rr = li >> 4, q = li & 15;
            int row = m0 + rr;
            float4 u = make_float4(0.f, 0.f, 0.f, 0.f);
            if (row < NN) u = *(const float4*)(A + (size_t)row * 64 + q * 4);
            *(float4*)(xt + rr * 68 + q * 4) = u;
        }
        __syncthreads();
#pragma unroll 8
        for (int k = 0; k < 64; k++) {
            float4 wv = *(const float4*)(wt + k * 64 + cg * 4);
#pragma unroll
            for (int r = 0; r < 8; r++) {
                float xv = xt[(rg * 8 + r) * 68 + k];
                acc[r][0] += xv * wv.x; acc[r][1] += xv * wv.y;
                acc[r][2] += xv * wv.z; acc[r][3] += xv * wv.w;
            }
        }
    }
#pragma unroll
    for (int r = 0; r < 8; r++) {
        int row = m0 + rg * 8 + r;
        if (row < NN) {
            float4 res;
            float* rp = &res.x;
#pragma unroll
            for (int j = 0; j < 4; j++)
                rp[j] = fmaxf(acc[r][j] + bias21[cg * 4 + j], 0.f);
            *(float4*)(y2 + (size_t)row * 64 + cg * 4) = res;
        }
    }
}

// ---------- K7: per-node scalars p = y2.Wl3, z = y2.Wr3 + bl3 ----------
__global__ __launch_bounds__(256) void k_proj(
    const float* __restrict__ y2,
    const float* __restrict__ Wl3, const float* __restrict__ bl3,
    const float* __restrict__ Wr3,
    float* __restrict__ pbuf, float* __restrict__ zbuf)
{
    __shared__ float wl[64], wr[64];
    int tid = threadIdx.x;
    if (tid < 64) { wl[tid] = Wl3[tid]; wr[tid] = Wr3[tid]; }
    __syncthreads();
    int t = blockIdx.x * 256 + tid;
    if (t >= NN) return;
    const float* row = y2 + (size_t)t * 64;
    float ap = 0.f, az = 0.f;
#pragma unroll
    for (int j = 0; j < 16; j++) {
        float4 u = *(const float4*)(row + j * 4);
        const float* wlp = wl + j * 4;
        const float* wrp = wr + j * 4;
        ap += u.x * wlp[0] + u.y * wlp[1] + u.z * wlp[2] + u.w * wlp[3];
        az += u.x * wrp[0] + u.y * wrp[1] + u.z * wrp[2] + u.w * wrp[3];
    }
    pbuf[t] = ap;
    zbuf[t] = az + bl3[0];
}

// ---------- K8: o[v] += mean(p[src]) + z[v] ----------
__global__ __launch_bounds__(256) void k_sage2(
    const int* __restrict__ rowptr, const int* __restrict__ sorted,
    const float* __restrict__ pbuf, const float* __restrict__ zbuf,
    const float* __restrict__ invcnt, float* __restrict__ o)
{
    int wid = threadIdx.x >> 6, lane = threadIdx.x & 63;
    int v = blockIdx.x * 4 + wid;
    if (v >= NN) return;
    int e0 = rowptr[v], e1 = rowptr[v + 1];
    float s = 0.f;
    for (int e = e0 + lane; e < e1; e += 64) s += pbuf[sorted[e]];
#pragma unroll
    for (int off = 32; off > 0; off >>= 1) s += __shfl_xor(s, off);
    if (lane == 0) o[v] += s * invcnt[v] + zbuf[v];
}

// ---------- K9: sigmoid ----------
__global__ __launch_bounds__(256) void k_sigmoid(const float* __restrict__ o,
                                                 float* __restrict__ out)
{
    int t = blockIdx.x * 256 + threadIdx.x;
    if (t >= NN) return;
    out[t] = 1.f / (1.f + expf(-o[t]));
}

// ---------- launch ----------
extern "C" void kernel_launch(void* const* d_in, const int* in_sizes, int n_in,
                              void* d_out, int out_size, void* d_ws, size_t ws_size,
                              hipStream_t stream)
{
    const float* x    = (const float*)d_in[0];
    const int* ei     = (const int*)d_in[1];
    const int* attr   = (const int*)d_in[2];
    const float* Wspf = (const float*)d_in[3];
    const float* bspf = (const float*)d_in[4];
    const float* W011 = (const float*)d_in[5];
    const float* b011 = (const float*)d_in[6];
    const float* W012 = (const float*)d_in[7];
    const float* b012 = (const float*)d_in[8];
    const float* bn01 = (const float*)d_in[9];
    const float* eW1[3] = { (const float*)d_in[10], (const float*)d_in[15], (const float*)d_in[20] };
    const float* eb1[3] = { (const float*)d_in[11], (const float*)d_in[16], (const float*)d_in[21] };
    const float* eW2[3] = { (const float*)d_in[12], (const float*)d_in[17], (const float*)d_in[22] };
    const float* eb2[3] = { (const float*)d_in[13], (const float*)d_in[18], (const float*)d_in[23] };
    const float* bn1[3] = { (const float*)d_in[14], (const float*)d_in[19], (const float*)d_in[24] };
    const float* s21Wl = (const float*)d_in[25];
    const float* s21bl = (const float*)d_in[26];
    const float* s21Wr = (const float*)d_in[27];
    const float* bn21  = (const float*)d_in[28];
    const float* s3Wl[3] = { (const float*)d_in[29], (const float*)d_in[32], (const float*)d_in[35] };
    const float* s3bl[3] = { (const float*)d_in[30], (const float*)d_in[33], (const float*)d_in[36] };
    const float* s3Wr[3] = { (const float*)d_in[31], (const float*)d_in[34], (const float*)d_in[37] };

    char* ws = (char*)d_ws;
    unsigned short* Whl = (unsigned short*)(ws + OFF_WHL);
    float* WspP   = (float*)(ws + OFF_WSPP);
    float* bias01 = (float*)(ws + OFF_BIAS01);
    float* W1pqT  = (float*)(ws + OFF_W1PQT);
    float* biasPQ = (float*)(ws + OFF_BIASPQ);
    float* WsageT = (float*)(ws + OFF_WSAGET);
    float* bias21 = (float*)(ws + OFF_BIAS21);
    float* bnf    = (float*)(ws + OFF_BNF);
    unsigned short* W2bf = (unsigned short*)(ws + OFF_W2BF);
    float* invcnt = (float*)(ws + OFF_INVCNT);
    float* pbuf   = (float*)(ws + OFF_PBUF);
    float* zbuf   = (float*)(ws + OFF_ZBUF);
    int*   rp3    = (int*)(ws + OFF_RP3);
    int*   parts  = (int*)(ws + OFF_PARTS);
    int*   deg3   = (int*)(ws + OFF_DEG3);
    int*   ghead  = (int*)(ws + OFF_GHEAD);
    float* o      = (float*)(ws + OFF_O);
    int*   sort3  = (int*)(ws + OFF_SORT3);
    unsigned int* ebuck3 = (unsigned int*)(ws + OFF_EBUCK3);
    float* h      = (float*)(ws + OFF_H);
    float* PQ     = (float*)(ws + OFF_PQ);
    float* y1     = (float*)(ws + OFF_Y1);
    float* aggp   = (float*)(ws + OFF_AGG);
    float* y2     = (float*)(ws + OFF_Y2);   // overlays PQ (dead by then)

    hipMemsetAsync(ws + OFF_DEG3, 0, 1400000, stream);

    k_prep<<<689, 256, 0, stream>>>(
        Wspf, bspf, W011, b011, W012, b012, bn01,
        eW1[0], eb1[0], eb2[0], bn1[0],
        eW1[1], eb1[1], eb2[1], bn1[1],
        eW1[2], eb1[2], eb2[2], bn1[2],
        eW2[0], eW2[1], eW2[2],
        s21Wl, s21bl, s21Wr, bn21,
        Whl, WspP, bias01, W1pqT, biasPQ, WsageT, bias21, bnf, W2bf);

    k_hist3<<<3907, 256, 0, stream>>>(ei + EE, attr, deg3);
    k_psum<<<dim3(196, 3), 256, 0, stream>>>(deg3, parts);
    k_pscan<<<1, 256, 0, stream>>>(parts);
    k_scanfix<<<dim3(196, 3), 256, 0, stream>>>(deg3, parts, rp3);
    k_gheadinit<<<3, 256, 0, stream>>>(rp3, ghead);
    k_bucketA<<<245, 256, 0, stream>>>(ei, ei + EE, attr, ghead, ebuck3);
    k_bucketB<<<dim3(NBK, 3), 256, 0, stream>>>(rp3, ebuck3, sort3);

    k_h<<<3125, 256, 0, stream>>>(x, Whl, WspP, bias01, h);

    for (int b = 0; b < 3; b++) {
        const int* rp = rp3 + b * RPSTRIDE;
        const int* so = sort3 + (size_t)b * EE;
        k_pq<<<782, 256, 0, stream>>>(h, W1pqT + b * 8192, biasPQ + b * 128, PQ);
        k_edgeconv<<<12500, 256, 0, stream>>>(rp, so, PQ, W2bf + b * 4096,
                                              bnf + b * 192, y1, invcnt);
        k_agg<<<12500, 256, 0, stream>>>(rp, so, y1, invcnt, aggp);
        k_sage1<<<391, 256, 0, stream>>>(aggp, y1, WsageT, bias21, y2);
        k_proj<<<196, 256, 0, stream>>>(y2, s3Wl[b], s3bl[b], s3Wr[b], pbuf, zbuf);
        k_sage2<<<12500, 256, 0, stream>>>(rp, so, pbuf, zbuf, invcnt, o);
    }
    k_sigmoid<<<196, 256, 0, stream>>>(o, (float*)d_out);
}